// Round 22
// baseline (349.354 us; speedup 1.0000x reference)
//
#include <hip/hip_runtime.h>
#include <hip/hip_bf16.h>
#include <math.h>

#define NPART 16  // s-blocks of 256: 64x16 = 1024 blocks (r18-proven)

typedef __attribute__((ext_vector_type(8))) short bf16x8;  // MFMA A/B frag (4 VGPR)
typedef __attribute__((ext_vector_type(4))) float f32x4;   // MFMA C/D frag

static __device__ inline ushort f2bf(float x) {
  __hip_bfloat16 h = __float2bfloat16(x);
  return *reinterpret_cast<ushort*>(&h);
}
static __device__ inline float bf2f(ushort u) {
  uint x = ((uint)u) << 16;
  return *reinterpret_cast<float*>(&x);
}

// ---------------------------------------------------------------------------
// PREP kernel (r21-proven): blocks [0,128) transpose-cast W; rest cast X.
// ---------------------------------------------------------------------------
__global__ __launch_bounds__(256) void prep_kernel(
    const float* __restrict__ W, ushort* __restrict__ Wt, int K, int D,
    const float* __restrict__ a, ushort* __restrict__ oa, size_t n4a,
    const float* __restrict__ b, ushort* __restrict__ ob, size_t n4b) {
  __shared__ float t[64][65];
  if (blockIdx.x < 128) {
    const int k0 = (blockIdx.x & 15) * 64, d0 = (blockIdx.x >> 4) * 64;
    const int r = threadIdx.x >> 6, c = threadIdx.x & 63;
#pragma unroll
    for (int i = 0; i < 16; i++)
      t[r + i * 4][c] = W[(size_t)(k0 + r + i * 4) * D + d0 + c];
    __syncthreads();
#pragma unroll
    for (int i = 0; i < 16; i++)
      Wt[(size_t)(d0 + r + i * 4) * K + k0 + c] = f2bf(t[c][r + i * 4]);
  } else {
    size_t i = (size_t)(blockIdx.x - 128) * blockDim.x + threadIdx.x;
    size_t stride = (size_t)(gridDim.x - 128) * blockDim.x;
    for (; i < n4a + n4b; i += stride) {
      const float4* src = (i < n4a) ? &((const float4*)a)[i]
                                    : &((const float4*)b)[i - n4a];
      ushort4* dst = (i < n4a) ? &((ushort4*)oa)[i] : &((ushort4*)ob)[i - n4a];
      float4 v = *src;
      ushort4 u;
      u.x = f2bf(v.x); u.y = f2bf(v.y); u.z = f2bf(v.z); u.w = f2bf(v.w);
      *dst = u;
    }
  }
}

// ---------------------------------------------------------------------------
// FUSED encoder GEMM (r16-proven): 512 thr, tile 128x256, 3-deep rotation.
// ---------------------------------------------------------------------------
#define ESTAGE(kt, pb)                                                        \
  {                                                                           \
    _Pragma("unroll")                                                         \
    for (int i_ = 0; i_ < 3; i_++) {                                          \
      const int seg_ = wave * 3 + i_;                                         \
      const ushort* src_ = (seg_ < 8)                                         \
          ? Xall + (row0 + seg_ * 16 + fr) * (size_t)K + (kt) * 32 + kg * 8   \
          : Wt + (d0 + (seg_ - 8) * 16 + fr) * (size_t)K + (kt) * 32 + kg * 8;\
      __builtin_amdgcn_global_load_lds(                                       \
          (const __attribute__((address_space(1))) void*)src_,                \
          (__attribute__((address_space(3))) void*)                           \
              &tile[(pb) * 12288 + seg_ * 512 + lane * 8],                    \
          16, 0, 0);                                                          \
    }                                                                         \
  }

__global__ __launch_bounds__(512, 4) void encode_mfma_kernel(
    const ushort* __restrict__ Xall, const ushort* __restrict__ Wt,
    const float* __restrict__ bias, float* __restrict__ emb,
    int K, int D) {
  __shared__ ushort tile[3 * 12288];
  const int tid = threadIdx.x;
  const int wave = tid >> 6, lane = tid & 63;
  const int fr = lane & 15, kg = lane >> 4;
  const int wr = wave >> 2, wc = wave & 3;
  const long row0 = (long)blockIdx.x * 128;
  const int d0 = blockIdx.y * 256;

  f32x4 acc[4][4];
#pragma unroll
  for (int rg = 0; rg < 4; rg++)
#pragma unroll
    for (int cg = 0; cg < 4; cg++) acc[rg][cg] = (f32x4){0.f, 0.f, 0.f, 0.f};

  ESTAGE(0, 0)
  ESTAGE(1, 1)
  int bcur = 0;
  for (int t = 0; t < 32; t++) {
    if (t < 31) asm volatile("s_waitcnt vmcnt(3)" ::: "memory");
    else        asm volatile("s_waitcnt vmcnt(0)" ::: "memory");
    __builtin_amdgcn_sched_barrier(0);
    __builtin_amdgcn_s_barrier();
    if (t < 30) {
      int bnext = bcur + 2; if (bnext >= 3) bnext -= 3;
      ESTAGE(t + 2, bnext)
    }
    const ushort* base = &tile[bcur * 12288];
    bf16x8 bfr[4];
#pragma unroll
    for (int cg = 0; cg < 4; cg++)
      bfr[cg] = *(const bf16x8*)&base[(8 + wc * 4 + cg) * 512 + lane * 8];
#pragma unroll
    for (int rg = 0; rg < 4; rg++) {
      bf16x8 af = *(const bf16x8*)&base[(wr * 4 + rg) * 512 + lane * 8];
#pragma unroll
      for (int cg = 0; cg < 4; cg++)
        acc[rg][cg] = __builtin_amdgcn_mfma_f32_16x16x32_bf16(
            af, bfr[cg], acc[rg][cg], 0, 0, 0);
    }
    bcur++; if (bcur == 3) bcur = 0;
  }
#pragma unroll
  for (int cg = 0; cg < 4; cg++) {
    const int col = d0 + wc * 64 + cg * 16 + fr;
    const float bl = bias[col];
#pragma unroll
    for (int rg = 0; rg < 4; rg++)
#pragma unroll
      for (int r = 0; r < 4; r++)
        emb[(row0 + wr * 64 + rg * 16 + kg * 4 + r) * (size_t)D + col] =
            acc[rg][cg][r] + bl;
  }
}

// ---------------------------------------------------------------------------
__global__ __launch_bounds__(256) void norm_bf16_kernel(
    const float* __restrict__ in, ushort* __restrict__ outb, int nrows, int D) {
  int row = (int)((blockIdx.x * blockDim.x + threadIdx.x) >> 6);
  int lane = threadIdx.x & 63;
  if (row >= nrows) return;
  const float4* p = (const float4*)(in + (size_t)row * D);
  float4 v0 = p[lane];
  float4 v1 = p[lane + 64];
  float ss = v0.x * v0.x + v0.y * v0.y + v0.z * v0.z + v0.w * v0.w
           + v1.x * v1.x + v1.y * v1.y + v1.z * v1.z + v1.w * v1.w;
#pragma unroll
  for (int off = 32; off > 0; off >>= 1) ss += __shfl_xor(ss, off);
  float inv = 1.0f / fmaxf(sqrtf(ss), 1e-12f);
  ushort4 u0, u1;
  u0.x = f2bf(v0.x * inv); u0.y = f2bf(v0.y * inv);
  u0.z = f2bf(v0.z * inv); u0.w = f2bf(v0.w * inv);
  u1.x = f2bf(v1.x * inv); u1.y = f2bf(v1.y * inv);
  u1.z = f2bf(v1.z * inv); u1.w = f2bf(v1.w * inv);
  ushort* o = outb + (size_t)row * D;
  *(ushort4*)(o + 4 * lane) = u0;
  *(ushort4*)(o + 256 + 4 * lane) = u1;
}

// ---------------------------------------------------------------------------
// MFMA attention (r18/r20/r21-proven, unchanged).
// ---------------------------------------------------------------------------
#define STAGE_BODY(kt, pb)                                                    \
  {                                                                           \
    _Pragma("unroll")                                                         \
    for (int i_ = 0; i_ < 3; i_++) {                                          \
      const int seg_ = wave * 3 + i_;                                         \
      const ushort* src_ = (seg_ < 8)                                         \
          ? Qb + (q0 + seg_ * 16 + fr) * (size_t)D + (kt) * 32 + kg * 8       \
          : Sb + (s0 + (seg_ - 8) * 16 + fr) * (size_t)D + (kt) * 32 + kg * 8;\
      __builtin_amdgcn_global_load_lds(                                       \
          (const __attribute__((address_space(1))) void*)src_,                \
          (__attribute__((address_space(3))) void*)                           \
              &tile[(pb) * 12288 + seg_ * 512 + lane * 8],                    \
          16, 0, 0);                                                          \
    }                                                                         \
  }

__global__ __launch_bounds__(512, 4) void attn_mfma_kernel(
    const ushort* __restrict__ Qb, const ushort* __restrict__ Sb,
    const int* __restrict__ labels, ushort* __restrict__ partial,
    int nq, int D) {
  __shared__ ushort tile[3 * 12288];
  __shared__ int lab[256];
  const int tid = threadIdx.x;
  const int wave = tid >> 6, lane = tid & 63;
  const int fr = lane & 15, kg = lane >> 4;
  const int wr = wave >> 2, wc = wave & 3;
  const long q0 = (long)blockIdx.x * 128;
  const int part = blockIdx.y;
  const long s0 = (long)part * 256;

  if (tid < 256) lab[tid] = labels[s0 + tid];

  f32x4 acc[4][4];
#pragma unroll
  for (int rg = 0; rg < 4; rg++)
#pragma unroll
    for (int cg = 0; cg < 4; cg++) acc[rg][cg] = (f32x4){0.f, 0.f, 0.f, 0.f};

  STAGE_BODY(0, 0)
  STAGE_BODY(1, 1)
  int bcur = 0;
  for (int t = 0; t < 16; t++) {
    if (t < 15) asm volatile("s_waitcnt vmcnt(3)" ::: "memory");
    else        asm volatile("s_waitcnt vmcnt(0)" ::: "memory");
    __builtin_amdgcn_sched_barrier(0);
    __builtin_amdgcn_s_barrier();
    if (t < 14) {
      int bnext = bcur + 2; if (bnext >= 3) bnext -= 3;
      STAGE_BODY(t + 2, bnext)
    }
    const ushort* base = &tile[bcur * 12288];
    bf16x8 bfr[4];
#pragma unroll
    for (int cg = 0; cg < 4; cg++)
      bfr[cg] = *(const bf16x8*)&base[(8 + wc * 4 + cg) * 512 + lane * 8];
#pragma unroll
    for (int rg = 0; rg < 4; rg++) {
      bf16x8 af = *(const bf16x8*)&base[(wr * 4 + rg) * 512 + lane * 8];
#pragma unroll
      for (int cg = 0; cg < 4; cg++)
        acc[rg][cg] = __builtin_amdgcn_mfma_f32_16x16x32_bf16(
            af, bfr[cg], acc[rg][cg], 0, 0, 0);
    }
    bcur++; if (bcur == 3) bcur = 0;
  }

  __syncthreads();
#pragma unroll
  for (int rg = 0; rg < 4; rg++)
#pragma unroll
    for (int cg = 0; cg < 4; cg++)
#pragma unroll
      for (int r = 0; r < 4; r++) {
        const int q  = wr * 64 + rg * 16 + kg * 4 + r;
        const int sc = wc * 64 + cg * 16 + fr;
        const int byteoff = ((q << 9) + (sc << 1)) ^ ((q & 7) << 4);
        *(ushort*)((char*)tile + byteoff) = f2bf(__expf(acc[rg][cg][r]));
      }
  __syncthreads();

  f32x4 acc2[4];
#pragma unroll
  for (int rg = 0; rg < 4; rg++) acc2[rg] = (f32x4){0.f, 0.f, 0.f, 0.f};
  const int cls = wc * 16 + fr;
#pragma unroll
  for (int t = 0; t < 8; t++) {
    const int kb = t * 32 + kg * 8;
    int4 l0 = *(const int4*)&lab[kb];
    int4 l1 = *(const int4*)&lab[kb + 4];
    uint b0 = ((l0.x == cls) ? 0x3F80u : 0u) | (((l0.y == cls) ? 0x3F80u : 0u) << 16);
    uint b1 = ((l0.z == cls) ? 0x3F80u : 0u) | (((l0.w == cls) ? 0x3F80u : 0u) << 16);
    uint b2 = ((l1.x == cls) ? 0x3F80u : 0u) | (((l1.y == cls) ? 0x3F80u : 0u) << 16);
    uint b3 = ((l1.z == cls) ? 0x3F80u : 0u) | (((l1.w == cls) ? 0x3F80u : 0u) << 16);
    uint4 bu = {b0, b1, b2, b3};
    bf16x8 bfr = *(bf16x8*)&bu;
#pragma unroll
    for (int rg = 0; rg < 4; rg++) {
      const int qrow = wr * 64 + rg * 16 + fr;
      const int byteoff = ((qrow << 9) + (kb << 1)) ^ ((qrow & 7) << 4);
      bf16x8 af = *(const bf16x8*)((char*)tile + byteoff);
      acc2[rg] = __builtin_amdgcn_mfma_f32_16x16x32_bf16(af, bfr, acc2[rg], 0, 0, 0);
    }
  }
#pragma unroll
  for (int rg = 0; rg < 4; rg++)
#pragma unroll
    for (int r = 0; r < 4; r++) {
      const long q = q0 + wr * 64 + rg * 16 + kg * 4 + r;
      partial[((size_t)part * nq + q) * 64 + cls] = f2bf(acc2[rg][r]);
    }
}

// ---------------------------------------------------------------------------
// DIAGNOSTIC A: phase-1 replica x4 (64 steps, staging cycles kt over 16).
// ---------------------------------------------------------------------------
__global__ __launch_bounds__(512, 4) void attn_p1_full(
    const ushort* __restrict__ Qb, const ushort* __restrict__ Sb,
    float* __restrict__ sink, int D) {
  __shared__ ushort tile[3 * 12288];
  const int tid = threadIdx.x;
  const int wave = tid >> 6, lane = tid & 63;
  const int fr = lane & 15, kg = lane >> 4;
  const int wr = wave >> 2, wc = wave & 3;
  const long q0 = (long)blockIdx.x * 128;
  const long s0 = (long)blockIdx.y * 256;

  f32x4 acc[4][4];
#pragma unroll
  for (int rg = 0; rg < 4; rg++)
#pragma unroll
    for (int cg = 0; cg < 4; cg++) acc[rg][cg] = (f32x4){0.f, 0.f, 0.f, 0.f};

  STAGE_BODY(0, 0)
  STAGE_BODY(1, 1)
  int bcur = 0;
  for (int t = 0; t < 64; t++) {     // x4 amplification
    if (t < 63) asm volatile("s_waitcnt vmcnt(3)" ::: "memory");
    else        asm volatile("s_waitcnt vmcnt(0)" ::: "memory");
    __builtin_amdgcn_sched_barrier(0);
    __builtin_amdgcn_s_barrier();
    if (t < 62) {
      int bnext = bcur + 2; if (bnext >= 3) bnext -= 3;
      STAGE_BODY((t + 2) & 15, bnext)
    }
    const ushort* base = &tile[bcur * 12288];
    bf16x8 bfr[4];
#pragma unroll
    for (int cg = 0; cg < 4; cg++)
      bfr[cg] = *(const bf16x8*)&base[(8 + wc * 4 + cg) * 512 + lane * 8];
#pragma unroll
    for (int rg = 0; rg < 4; rg++) {
      bf16x8 af = *(const bf16x8*)&base[(wr * 4 + rg) * 512 + lane * 8];
#pragma unroll
      for (int cg = 0; cg < 4; cg++)
        acc[rg][cg] = __builtin_amdgcn_mfma_f32_16x16x32_bf16(
            af, bfr[cg], acc[rg][cg], 0, 0, 0);
    }
    bcur++; if (bcur == 3) bcur = 0;
  }
  float s = 0.f;
#pragma unroll
  for (int rg = 0; rg < 4; rg++)
#pragma unroll
    for (int cg = 0; cg < 4; cg++)
#pragma unroll
      for (int r = 0; r < 4; r++) s += acc[rg][cg][r];
  asm volatile("" :: "v"(s));
  if (s == -1234.5f) sink[tid] = s;
}

// ---------------------------------------------------------------------------
// DIAGNOSTIC B: phase-1 compute floor x4 — NO staging, NO vmcnt. Same
// barriers, ds_reads, MFMAs on a pre-zeroed tile. Measures the pure
// barrier+dsread+MFMA rhythm cost.
// ---------------------------------------------------------------------------
__global__ __launch_bounds__(512, 4) void attn_p1_nostage(
    float* __restrict__ sink) {
  __shared__ ushort tile[3 * 12288];
  const int tid = threadIdx.x;
  const int wave = tid >> 6, lane = tid & 63;
  const int wr = wave >> 2, wc = wave & 3;
  for (int i = tid; i < 3 * 12288 / 2; i += 512) ((uint*)tile)[i] = 0x3F803F80u;
  __syncthreads();

  f32x4 acc[4][4];
#pragma unroll
  for (int rg = 0; rg < 4; rg++)
#pragma unroll
    for (int cg = 0; cg < 4; cg++) acc[rg][cg] = (f32x4){0.f, 0.f, 0.f, 0.f};

  int bcur = 0;
  for (int t = 0; t < 64; t++) {     // x4 amplification
    __builtin_amdgcn_s_barrier();
    const ushort* base = &tile[bcur * 12288];
    bf16x8 bfr[4];
#pragma unroll
    for (int cg = 0; cg < 4; cg++)
      bfr[cg] = *(const bf16x8*)&base[(8 + wc * 4 + cg) * 512 + lane * 8];
#pragma unroll
    for (int rg = 0; rg < 4; rg++) {
      bf16x8 af = *(const bf16x8*)&base[(wr * 4 + rg) * 512 + lane * 8];
#pragma unroll
      for (int cg = 0; cg < 4; cg++)
        acc[rg][cg] = __builtin_amdgcn_mfma_f32_16x16x32_bf16(
            af, bfr[cg], acc[rg][cg], 0, 0, 0);
    }
    bcur++; if (bcur == 3) bcur = 0;
  }
  float s = 0.f;
#pragma unroll
  for (int rg = 0; rg < 4; rg++)
#pragma unroll
    for (int cg = 0; cg < 4; cg++)
#pragma unroll
      for (int r = 0; r < 4; r++) s += acc[rg][cg][r];
  asm volatile("" :: "v"(s));
  if (s == -1234.5f) sink[tid] = s;
}

// ---------------------------------------------------------------------------
__global__ __launch_bounds__(256) void combine_kernel(
    const ushort* __restrict__ partial, float* __restrict__ out, int nq, int nsplit) {
  int q = (int)((blockIdx.x * blockDim.x + threadIdx.x) >> 6);
  int lane = threadIdx.x & 63;
  if (q >= nq) return;
  float v = 0.0f;
  for (int h = 0; h < nsplit; h++)
    v += bf2f(partial[((size_t)h * nq + q) * 64 + lane]);
  float s = v;
#pragma unroll
  for (int off = 32; off > 0; off >>= 1) s += __shfl_xor(s, off);
  out[(size_t)q * 64 + lane] = v / s;
}

// ---------------------------------------------------------------------------
// Workspace as r21; diagnostics run after combine (everything dead), sink at
// [46M,47M). d_out untouched by diagnostics.
// ---------------------------------------------------------------------------
extern "C" void kernel_launch(void* const* d_in, const int* in_sizes, int n_in,
                              void* d_out, int out_size, void* d_ws, size_t ws_size,
                              hipStream_t stream) {
  const float* support = (const float*)d_in[0];
  const float* query   = (const float*)d_in[1];
  const float* W       = (const float*)d_in[2];
  const float* b       = (const float*)d_in[3];
  const int*   labels  = (const int*)d_in[4];

  const int d_dim    = in_sizes[3];            // 512
  const int in_dim   = in_sizes[2] / d_dim;    // 1024
  const int n_support = in_sizes[0] / in_dim;  // 4096
  const int n_query   = in_sizes[1] / in_dim;  // 8192
  const int n_all     = n_support + n_query;   // 12288

  char* base = (char*)d_ws;
  ushort* xb_s  = (ushort*)(base);
  ushort* xb_q  = (ushort*)(base + ((size_t)8 << 20));
  ushort* Wt    = (ushort*)(base + ((size_t)24 << 20));
  float*  s_emb = (float*)(base + ((size_t)25 << 20));
  float*  q_emb = (float*)(base + ((size_t)33 << 20));
  ushort* s_bf  = (ushort*)(base);
  ushort* q_bf  = (ushort*)(base + ((size_t)4 << 20));
  ushort* partial = (ushort*)(base + ((size_t)12 << 20));
  float*  sink    = (float*)(base + ((size_t)46 << 20));

  dim3 blk(256);
  prep_kernel<<<2176, blk, 0, stream>>>(
      W, Wt, in_dim, d_dim,
      support, xb_s, (size_t)n_support * in_dim / 4,
      query, xb_q, (size_t)n_query * in_dim / 4);
  encode_mfma_kernel<<<dim3(n_all / 128, d_dim / 256), dim3(512), 0, stream>>>(
      xb_s, Wt, b, s_emb, in_dim, d_dim);
  norm_bf16_kernel<<<dim3(n_all / 4), blk, 0, stream>>>(s_emb, s_bf, n_all, d_dim);
  attn_mfma_kernel<<<dim3(n_query / 128, NPART), dim3(512), 0, stream>>>(
      q_bf, s_bf, labels, partial, n_query, d_dim);
  combine_kernel<<<dim3(n_query / 4), blk, 0, stream>>>(partial, (float*)d_out, n_query, NPART);

  // ---- diagnostics (output-dead): attribute phase-1's 43 us ----
  attn_p1_full<<<dim3(n_query / 128, NPART), dim3(512), 0, stream>>>(
      q_bf, s_bf, sink, d_dim);                 // ~4x phase-1
  attn_p1_nostage<<<dim3(n_query / 128, NPART), dim3(512), 0, stream>>>(
      sink);                                    // ~4x compute floor
}

// Round 23
// 114.754 us; speedup vs baseline: 3.0444x; 3.0444x over previous
//
#include <hip/hip_runtime.h>
#include <hip/hip_bf16.h>
#include <math.h>

#define NPART 16  // s-blocks of 256; attn grid 1024 blocks, XCD-swizzled

typedef __attribute__((ext_vector_type(8))) short bf16x8;  // MFMA A/B frag (4 VGPR)
typedef __attribute__((ext_vector_type(4))) float f32x4;   // MFMA C/D frag

static __device__ inline ushort f2bf(float x) {
  __hip_bfloat16 h = __float2bfloat16(x);
  return *reinterpret_cast<ushort*>(&h);
}
static __device__ inline float bf2f(ushort u) {
  uint x = ((uint)u) << 16;
  return *reinterpret_cast<float*>(&x);
}

// ---------------------------------------------------------------------------
// PREP kernel (r21-proven): blocks [0,128) transpose-cast W; rest cast X.
// ---------------------------------------------------------------------------
__global__ __launch_bounds__(256) void prep_kernel(
    const float* __restrict__ W, ushort* __restrict__ Wt, int K, int D,
    const float* __restrict__ a, ushort* __restrict__ oa, size_t n4a,
    const float* __restrict__ b, ushort* __restrict__ ob, size_t n4b) {
  __shared__ float t[64][65];
  if (blockIdx.x < 128) {
    const int k0 = (blockIdx.x & 15) * 64, d0 = (blockIdx.x >> 4) * 64;
    const int r = threadIdx.x >> 6, c = threadIdx.x & 63;
#pragma unroll
    for (int i = 0; i < 16; i++)
      t[r + i * 4][c] = W[(size_t)(k0 + r + i * 4) * D + d0 + c];
    __syncthreads();
#pragma unroll
    for (int i = 0; i < 16; i++)
      Wt[(size_t)(d0 + r + i * 4) * K + k0 + c] = f2bf(t[c][r + i * 4]);
  } else {
    size_t i = (size_t)(blockIdx.x - 128) * blockDim.x + threadIdx.x;
    size_t stride = (size_t)(gridDim.x - 128) * blockDim.x;
    for (; i < n4a + n4b; i += stride) {
      const float4* src = (i < n4a) ? &((const float4*)a)[i]
                                    : &((const float4*)b)[i - n4a];
      ushort4* dst = (i < n4a) ? &((ushort4*)oa)[i] : &((ushort4*)ob)[i - n4a];
      float4 v = *src;
      ushort4 u;
      u.x = f2bf(v.x); u.y = f2bf(v.y); u.z = f2bf(v.z); u.w = f2bf(v.w);
      *dst = u;
    }
  }
}

// ---------------------------------------------------------------------------
// FUSED encoder GEMM (r16-proven): 512 thr, tile 128x256, 3-deep rotation.
// ---------------------------------------------------------------------------
#define ESTAGE(kt, pb)                                                        \
  {                                                                           \
    _Pragma("unroll")                                                         \
    for (int i_ = 0; i_ < 3; i_++) {                                          \
      const int seg_ = wave * 3 + i_;                                         \
      const ushort* src_ = (seg_ < 8)                                         \
          ? Xall + (row0 + seg_ * 16 + fr) * (size_t)K + (kt) * 32 + kg * 8   \
          : Wt + (d0 + (seg_ - 8) * 16 + fr) * (size_t)K + (kt) * 32 + kg * 8;\
      __builtin_amdgcn_global_load_lds(                                       \
          (const __attribute__((address_space(1))) void*)src_,                \
          (__attribute__((address_space(3))) void*)                           \
              &tile[(pb) * 12288 + seg_ * 512 + lane * 8],                    \
          16, 0, 0);                                                          \
    }                                                                         \
  }

__global__ __launch_bounds__(512, 4) void encode_mfma_kernel(
    const ushort* __restrict__ Xall, const ushort* __restrict__ Wt,
    const float* __restrict__ bias, float* __restrict__ emb,
    int K, int D) {
  __shared__ ushort tile[3 * 12288];
  const int tid = threadIdx.x;
  const int wave = tid >> 6, lane = tid & 63;
  const int fr = lane & 15, kg = lane >> 4;
  const int wr = wave >> 2, wc = wave & 3;
  const long row0 = (long)blockIdx.x * 128;
  const int d0 = blockIdx.y * 256;

  f32x4 acc[4][4];
#pragma unroll
  for (int rg = 0; rg < 4; rg++)
#pragma unroll
    for (int cg = 0; cg < 4; cg++) acc[rg][cg] = (f32x4){0.f, 0.f, 0.f, 0.f};

  ESTAGE(0, 0)
  ESTAGE(1, 1)
  int bcur = 0;
  for (int t = 0; t < 32; t++) {
    if (t < 31) asm volatile("s_waitcnt vmcnt(3)" ::: "memory");
    else        asm volatile("s_waitcnt vmcnt(0)" ::: "memory");
    __builtin_amdgcn_sched_barrier(0);
    __builtin_amdgcn_s_barrier();
    if (t < 30) {
      int bnext = bcur + 2; if (bnext >= 3) bnext -= 3;
      ESTAGE(t + 2, bnext)
    }
    const ushort* base = &tile[bcur * 12288];
    bf16x8 bfr[4];
#pragma unroll
    for (int cg = 0; cg < 4; cg++)
      bfr[cg] = *(const bf16x8*)&base[(8 + wc * 4 + cg) * 512 + lane * 8];
#pragma unroll
    for (int rg = 0; rg < 4; rg++) {
      bf16x8 af = *(const bf16x8*)&base[(wr * 4 + rg) * 512 + lane * 8];
#pragma unroll
      for (int cg = 0; cg < 4; cg++)
        acc[rg][cg] = __builtin_amdgcn_mfma_f32_16x16x32_bf16(
            af, bfr[cg], acc[rg][cg], 0, 0, 0);
    }
    bcur++; if (bcur == 3) bcur = 0;
  }
#pragma unroll
  for (int cg = 0; cg < 4; cg++) {
    const int col = d0 + wc * 64 + cg * 16 + fr;
    const float bl = bias[col];
#pragma unroll
    for (int rg = 0; rg < 4; rg++)
#pragma unroll
      for (int r = 0; r < 4; r++)
        emb[(row0 + wr * 64 + rg * 16 + kg * 4 + r) * (size_t)D + col] =
            acc[rg][cg][r] + bl;
  }
}

// ---------------------------------------------------------------------------
__global__ __launch_bounds__(256) void norm_bf16_kernel(
    const float* __restrict__ in, ushort* __restrict__ outb, int nrows, int D) {
  int row = (int)((blockIdx.x * blockDim.x + threadIdx.x) >> 6);
  int lane = threadIdx.x & 63;
  if (row >= nrows) return;
  const float4* p = (const float4*)(in + (size_t)row * D);
  float4 v0 = p[lane];
  float4 v1 = p[lane + 64];
  float ss = v0.x * v0.x + v0.y * v0.y + v0.z * v0.z + v0.w * v0.w
           + v1.x * v1.x + v1.y * v1.y + v1.z * v1.z + v1.w * v1.w;
#pragma unroll
  for (int off = 32; off > 0; off >>= 1) ss += __shfl_xor(ss, off);
  float inv = 1.0f / fmaxf(sqrtf(ss), 1e-12f);
  ushort4 u0, u1;
  u0.x = f2bf(v0.x * inv); u0.y = f2bf(v0.y * inv);
  u0.z = f2bf(v0.z * inv); u0.w = f2bf(v0.w * inv);
  u1.x = f2bf(v1.x * inv); u1.y = f2bf(v1.y * inv);
  u1.z = f2bf(v1.z * inv); u1.w = f2bf(v1.w * inv);
  ushort* o = outb + (size_t)row * D;
  *(ushort4*)(o + 4 * lane) = u0;
  *(ushort4*)(o + 256 + 4 * lane) = u1;
}

// ---------------------------------------------------------------------------
// MFMA attention — r18/r21 body unchanged; NEW: XCD-aware block remap (T1).
// r22 diagnostic: 80% of phase-1 = staging wait at 95% L2-hit but congested
// latency; old mapping put each Q-tile's 16 blocks on ONE XCD and required
// all of S (4MB) + 1MB Q per XCD L2 (5MB > 4MB, thrash). New mapping gives
// each XCD 16 q-tiles (2MB) x 8 parts (2MB S) = 4MB, L2-resident.
// bid -> (qt, part) bijective: xcd=bid&7, idx=bid>>3,
// qt=(xcd&3)*16+(idx&15), part=(xcd>>2)*8+(idx>>4).
// Pure index remap; math and partial layout identical.
// ---------------------------------------------------------------------------
#define STAGE_BODY(kt, pb)                                                    \
  {                                                                           \
    _Pragma("unroll")                                                         \
    for (int i_ = 0; i_ < 3; i_++) {                                          \
      const int seg_ = wave * 3 + i_;                                         \
      const ushort* src_ = (seg_ < 8)                                         \
          ? Qb + (q0 + seg_ * 16 + fr) * (size_t)D + (kt) * 32 + kg * 8       \
          : Sb + (s0 + (seg_ - 8) * 16 + fr) * (size_t)D + (kt) * 32 + kg * 8;\
      __builtin_amdgcn_global_load_lds(                                       \
          (const __attribute__((address_space(1))) void*)src_,                \
          (__attribute__((address_space(3))) void*)                           \
              &tile[(pb) * 12288 + seg_ * 512 + lane * 8],                    \
          16, 0, 0);                                                          \
    }                                                                         \
  }

__global__ __launch_bounds__(512, 4) void attn_mfma_kernel(
    const ushort* __restrict__ Qb, const ushort* __restrict__ Sb,
    const int* __restrict__ labels, ushort* __restrict__ partial,
    int nq, int D) {
  __shared__ ushort tile[3 * 12288];
  __shared__ int lab[256];
  const int tid = threadIdx.x;
  const int wave = tid >> 6, lane = tid & 63;
  const int fr = lane & 15, kg = lane >> 4;
  const int wr = wave >> 2, wc = wave & 3;
  // ---- XCD-aware decode (bijective remap of 1024 blocks) ----
  const int bid = blockIdx.x;
  const int xcd = bid & 7, idx = bid >> 3;
  const int qt   = (xcd & 3) * 16 + (idx & 15);   // 0..63
  const int part = (xcd >> 2) * 8 + (idx >> 4);   // 0..15
  const long q0 = (long)qt * 128;
  const long s0 = (long)part * 256;

  if (tid < 256) lab[tid] = labels[s0 + tid];

  f32x4 acc[4][4];
#pragma unroll
  for (int rg = 0; rg < 4; rg++)
#pragma unroll
    for (int cg = 0; cg < 4; cg++) acc[rg][cg] = (f32x4){0.f, 0.f, 0.f, 0.f};

  // ---- phase 1: score GEMM, 3-deep counted-vmcnt pipeline ----
  STAGE_BODY(0, 0)
  STAGE_BODY(1, 1)
  int bcur = 0;
  for (int t = 0; t < 16; t++) {
    if (t < 15) asm volatile("s_waitcnt vmcnt(3)" ::: "memory");
    else        asm volatile("s_waitcnt vmcnt(0)" ::: "memory");
    __builtin_amdgcn_sched_barrier(0);
    __builtin_amdgcn_s_barrier();
    if (t < 14) {
      int bnext = bcur + 2; if (bnext >= 3) bnext -= 3;
      STAGE_BODY(t + 2, bnext)
    }
    const ushort* base = &tile[bcur * 12288];
    bf16x8 bfr[4];
#pragma unroll
    for (int cg = 0; cg < 4; cg++)
      bfr[cg] = *(const bf16x8*)&base[(8 + wc * 4 + cg) * 512 + lane * 8];
#pragma unroll
    for (int rg = 0; rg < 4; rg++) {
      bf16x8 af = *(const bf16x8*)&base[(wr * 4 + rg) * 512 + lane * 8];
#pragma unroll
      for (int cg = 0; cg < 4; cg++)
        acc[rg][cg] = __builtin_amdgcn_mfma_f32_16x16x32_bf16(
            af, bfr[cg], acc[rg][cg], 0, 0, 0);
    }
    bcur++; if (bcur == 3) bcur = 0;
  }

  // ---- phase 2: P = exp(S) bf16 -> swizzled LDS ----
  __syncthreads();
#pragma unroll
  for (int rg = 0; rg < 4; rg++)
#pragma unroll
    for (int cg = 0; cg < 4; cg++)
#pragma unroll
      for (int r = 0; r < 4; r++) {
        const int q  = wr * 64 + rg * 16 + kg * 4 + r;
        const int sc = wc * 64 + cg * 16 + fr;
        const int byteoff = ((q << 9) + (sc << 1)) ^ ((q & 7) << 4);
        *(ushort*)((char*)tile + byteoff) = f2bf(__expf(acc[rg][cg][r]));
      }
  __syncthreads();

  // ---- phase 3: out = P @ onehot, K=256 (8 k-steps) ----
  f32x4 acc2[4];
#pragma unroll
  for (int rg = 0; rg < 4; rg++) acc2[rg] = (f32x4){0.f, 0.f, 0.f, 0.f};
  const int cls = wc * 16 + fr;
#pragma unroll
  for (int t = 0; t < 8; t++) {
    const int kb = t * 32 + kg * 8;
    int4 l0 = *(const int4*)&lab[kb];
    int4 l1 = *(const int4*)&lab[kb + 4];
    uint b0 = ((l0.x == cls) ? 0x3F80u : 0u) | (((l0.y == cls) ? 0x3F80u : 0u) << 16);
    uint b1 = ((l0.z == cls) ? 0x3F80u : 0u) | (((l0.w == cls) ? 0x3F80u : 0u) << 16);
    uint b2 = ((l1.x == cls) ? 0x3F80u : 0u) | (((l1.y == cls) ? 0x3F80u : 0u) << 16);
    uint b3 = ((l1.z == cls) ? 0x3F80u : 0u) | (((l1.w == cls) ? 0x3F80u : 0u) << 16);
    uint4 bu = {b0, b1, b2, b3};
    bf16x8 bfr = *(bf16x8*)&bu;
#pragma unroll
    for (int rg = 0; rg < 4; rg++) {
      const int qrow = wr * 64 + rg * 16 + fr;
      const int byteoff = ((qrow << 9) + (kb << 1)) ^ ((qrow & 7) << 4);
      bf16x8 af = *(const bf16x8*)((char*)tile + byteoff);
      acc2[rg] = __builtin_amdgcn_mfma_f32_16x16x32_bf16(af, bfr, acc2[rg], 0, 0, 0);
    }
  }
#pragma unroll
  for (int rg = 0; rg < 4; rg++)
#pragma unroll
    for (int r = 0; r < 4; r++) {
      const long q = q0 + wr * 64 + rg * 16 + kg * 4 + r;
      partial[((size_t)part * nq + q) * 64 + cls] = f2bf(acc2[rg][r]);
    }
}

// ---------------------------------------------------------------------------
__global__ __launch_bounds__(256) void combine_kernel(
    const ushort* __restrict__ partial, float* __restrict__ out, int nq, int nsplit) {
  int q = (int)((blockIdx.x * blockDim.x + threadIdx.x) >> 6);
  int lane = threadIdx.x & 63;
  if (q >= nq) return;
  float v = 0.0f;
  for (int h = 0; h < nsplit; h++)
    v += bf2f(partial[((size_t)h * nq + q) * 64 + lane]);
  float s = v;
#pragma unroll
  for (int off = 32; off > 0; off >>= 1) s += __shfl_xor(s, off);
  out[(size_t)q * 64 + lane] = v / s;
}

// ---------------------------------------------------------------------------
// Workspace (r21-proven): [0,8M) xb_s  [8M,24M) xb_q  [24M,25M) Wt
// [25M,33M) s_emb  [33M,49M) q_emb; after encode+norm: s_bf [0,4M),
// q_bf [4M,12M), partial (bf16, 16MB) [12M,28M). All regions rewritten
// every call; d_out fully overwritten by combine.
// ---------------------------------------------------------------------------
extern "C" void kernel_launch(void* const* d_in, const int* in_sizes, int n_in,
                              void* d_out, int out_size, void* d_ws, size_t ws_size,
                              hipStream_t stream) {
  const float* support = (const float*)d_in[0];
  const float* query   = (const float*)d_in[1];
  const float* W       = (const float*)d_in[2];
  const float* b       = (const float*)d_in[3];
  const int*   labels  = (const int*)d_in[4];

  const int d_dim    = in_sizes[3];            // 512
  const int in_dim   = in_sizes[2] / d_dim;    // 1024
  const int n_support = in_sizes[0] / in_dim;  // 4096
  const int n_query   = in_sizes[1] / in_dim;  // 8192
  const int n_all     = n_support + n_query;   // 12288

  char* base = (char*)d_ws;
  ushort* xb_s  = (ushort*)(base);
  ushort* xb_q  = (ushort*)(base + ((size_t)8 << 20));
  ushort* Wt    = (ushort*)(base + ((size_t)24 << 20));
  float*  s_emb = (float*)(base + ((size_t)25 << 20));
  float*  q_emb = (float*)(base + ((size_t)33 << 20));
  ushort* s_bf  = (ushort*)(base);
  ushort* q_bf  = (ushort*)(base + ((size_t)4 << 20));
  ushort* partial = (ushort*)(base + ((size_t)12 << 20));

  dim3 blk(256);
  prep_kernel<<<2176, blk, 0, stream>>>(
      W, Wt, in_dim, d_dim,
      support, xb_s, (size_t)n_support * in_dim / 4,
      query, xb_q, (size_t)n_query * in_dim / 4);
  encode_mfma_kernel<<<dim3(n_all / 128, d_dim / 256), dim3(512), 0, stream>>>(
      xb_s, Wt, b, s_emb, in_dim, d_dim);
  norm_bf16_kernel<<<dim3(n_all / 4), blk, 0, stream>>>(s_emb, s_bf, n_all, d_dim);
  attn_mfma_kernel<<<dim3(n_query / 128 * NPART), dim3(512), 0, stream>>>(
      q_bf, s_bf, labels, partial, n_query, d_dim);
  combine_kernel<<<dim3(n_query / 4), blk, 0, stream>>>(partial, (float*)d_out, n_query, NPART);
}